// Round 8
// baseline (250.279 us; speedup 1.0000x reference)
//
#include <hip/hip_runtime.h>
#include <hip/hip_bf16.h>
#include <stdint.h>

typedef __attribute__((ext_vector_type(16))) float f32x16;
typedef __attribute__((ext_vector_type(8))) short bf16x8;
typedef __attribute__((ext_vector_type(4))) float float4v;

static constexpr int KD    = 1024;   // hidden dim
static constexpr int ND    = 2048;   // expert out dim (gate+up)
static constexpr int NE    = 8;      // experts
static constexpr int MROWS = 16384;  // hidden rows
static constexpr int RFLAT = 32768;  // M * topk
static constexpr int OUTN  = 1024;   // output cols (ND/2)

// ws ints: cnt[8]@0, cursor[8]@8, offs[9]@16, mode@31, tileoff[9]@40
static constexpr size_t WS_ROWLIST = 1024;
static constexpr size_t WS_HB      = 262144;
static constexpr size_t WS_WT      = 262144 + (size_t)33554432;

__device__ __forceinline__ unsigned short f2bf(float f) {
  uint32_t u = __float_as_uint(f);
  uint32_t r = (u + 0x7FFFu + ((u >> 16) & 1u)) >> 16;
  return (unsigned short)r;
}

__device__ __forceinline__ void gload16(const void* g, void* l) {
  __builtin_amdgcn_global_load_lds(
      (__attribute__((address_space(1))) void*)(void*)g,
      (__attribute__((address_space(3))) void*)l, 16, 0, 0);
}

// Detect int32-converted vs raw-int64 ids (odd 32-bit slots all zero => int64).
__global__ void k_detect(const int* __restrict__ ids32, int* __restrict__ wsi) {
  int t = blockIdx.x * 256 + threadIdx.x;
  int i = 2 * t + 1;
  if (i < RFLAT && ids32[i] != 0) atomicOr(&wsi[31], 1);
}

__device__ __forceinline__ int read_id(const int* ids32, int t, int mode) {
  return (mode ? ids32[t] : ids32[2 * t]) & 7;
}

// LDS-histogram count.
__global__ void k_count(const int* __restrict__ ids, int* __restrict__ wsi) {
  __shared__ int h[8];
  const int tid = threadIdx.x;
  if (tid < 8) h[tid] = 0;
  __syncthreads();
  const int mode = wsi[31];
  const int base = blockIdx.x * 512 + tid;
  atomicAdd(&h[read_id(ids, base, mode)], 1);
  atomicAdd(&h[read_id(ids, base + 256, mode)], 1);
  __syncthreads();
  if (tid < 8 && h[tid]) atomicAdd(&wsi[tid], h[tid]);
}

__global__ void k_scan(int* wsi) {
  if (threadIdx.x == 0) {
    int o = 0, to = 0;
    for (int e = 0; e < NE; ++e) {
      int c = wsi[e];
      wsi[16 + e] = o;   // offs
      wsi[8 + e]  = o;   // cursor
      wsi[40 + e] = to;  // tile offset (256-row tiles)
      o += c;
      to += (c + 255) / 256;
    }
    wsi[16 + NE] = o;
    wsi[40 + NE] = to;
  }
}

// LDS-histogram scatter: per-block base + local rank.
__global__ void k_scatter(const int* __restrict__ ids, int* __restrict__ wsi,
                          int* __restrict__ rowlist) {
  __shared__ int h[8], base[8], c2[8];
  const int tid = threadIdx.x;
  if (tid < 8) { h[tid] = 0; c2[tid] = 0; }
  __syncthreads();
  const int mode = wsi[31];
  const int t = blockIdx.x * 256 + tid;
  const int e = read_id(ids, t, mode);
  atomicAdd(&h[e], 1);
  __syncthreads();
  if (tid < 8 && h[tid]) base[tid] = atomicAdd(&wsi[8 + tid], h[tid]);
  __syncthreads();
  const int r = atomicAdd(&c2[e], 1);
  rowlist[base[e] + r] = t;
}

__global__ void k_cvtH(const float* __restrict__ H, unsigned short* __restrict__ Hb) {
  const int n4 = (MROWS * KD) / 4;
  const int stride = gridDim.x * blockDim.x;
  for (int i = blockIdx.x * blockDim.x + threadIdx.x; i < n4; i += stride) {
    float4v v = ((const float4v*)H)[i];
    ushort4 o;
    o.x = f2bf(v.x); o.y = f2bf(v.y); o.z = f2bf(v.z); o.w = f2bf(v.w);
    ((ushort4*)Hb)[i] = o;
  }
}

// Transpose + convert: W[e][k][n] fp32 -> Wt[e][n][k] bf16 (64x64 tiles).
__global__ void k_cvtW(const float* __restrict__ W, unsigned short* __restrict__ Wt) {
  __shared__ float tile[64][65];
  const int e  = blockIdx.z;
  const int n0 = blockIdx.x * 64;
  const int k0 = blockIdx.y * 64;
  const int tx = threadIdx.x, ty = threadIdx.y;
  const float* Wp = W + (size_t)e * KD * ND;
  #pragma unroll
  for (int i = ty; i < 64; i += 8)
    tile[i][tx] = Wp[(size_t)(k0 + i) * ND + n0 + tx];
  __syncthreads();
  unsigned short* Wo = Wt + (size_t)e * ND * KD;
  #pragma unroll
  for (int i = ty; i < 64; i += 8)
    Wo[(size_t)(n0 + i) * KD + k0 + tx] = f2bf(tile[tx][i]);
}

// Grouped GEMM: 4-phase counted-vmcnt schedule, 32x32x16 MFMA.
// 256 rows x 256 wcols, BK=64, 16 K-tiles, 512 threads = 8 waves (2Mx4N),
// wave tile 128 rows x 64 wcols = 4 m-frags x 2 n-frags of 32x32.
// n-frag 0 = gate cols, n-frag 1 = up cols (same 32 out-cols) -> silu pairs
// element-wise per acc register. LDS: 2 dbuf x 64KB, quarters of 64B-k;
// slot s of row r holds global chunk s ^ ((r>>1)&3) (2-way-free b128 reads,
// linear gload dest + pre-swizzled source, rule 21).
// Per phase: {4|8 ds_read_b128 ; stage 1 half (2 gloads)} -> [vmcnt(4) @P2,P4]
// -> barrier -> setprio(1) 8 MFMA setprio(0) -> barrier.
__global__ __launch_bounds__(512, 2) void k_gemm(
    const unsigned short* __restrict__ Hb, const unsigned short* __restrict__ Wt,
    const int* __restrict__ wsi, const int* __restrict__ rowlist,
    float* __restrict__ Out) {
  const int bid = blockIdx.x;
  const int xcd = bid & 7;
  const int j   = bid >> 3;
  const int colblk = j & 7;        // col-blocks fastest within an XCD
  const int rt  = xcd + (j >> 3) * 8;
  if (rt >= wsi[48]) return;
  int e = 0;
  #pragma unroll
  for (int q = 1; q < 8; ++q)
    if (rt >= wsi[40 + q]) e = q;
  const int cnt = wsi[e];
  const int tile_base = (rt - wsi[40 + e]) * 256;
  const int tile_cnt = min(256, cnt - tile_base);
  const int off = wsi[16 + e] + tile_base;
  const int c0 = colblk * 128;     // out-col base

  __shared__ char lds[131072];
  __shared__ int s_rows[256];

  const int t = threadIdx.x;
  if (t < 256) s_rows[t] = rowlist[off + min(t, tile_cnt - 1)];
  __syncthreads();

  // Staging: thread t covers rows/cols (t>>2) and 128+(t>>2), slot t&3.
  // Source chunk = (t&3) ^ ((t>>3)&3) pre-applies read swizzle sigma(r)=(r>>1)&3.
  const int srow = t >> 2;
  const int coff = ((t & 3) ^ ((t >> 3) & 3)) * 16;
  const char* sA0 = (const char*)Hb + (size_t)(s_rows[srow] >> 1) * (KD * 2) + coff;
  const char* sA1 = (const char*)Hb + (size_t)(s_rows[128 + srow] >> 1) * (KD * 2) + coff;
  // B LDS col jc: wave = jc>>6, n-frag = (jc&63)>>5, within = jc&31.
  auto wcol_of = [&](int jc) {
    const int wn_s = jc >> 6, jf = (jc & 63) >> 5, cl = jc & 31;
    return (jf == 0) ? (c0 + wn_s * 32 + cl) : (OUTN + c0 + wn_s * 32 + cl);
  };
  const char* sB0 = (const char*)Wt + ((size_t)e * ND + wcol_of(srow)) * (KD * 2) + coff;
  const char* sB1 = (const char*)Wt + ((size_t)e * ND + wcol_of(128 + srow)) * (KD * 2) + coff;

  const int lane = t & 63, wid = t >> 6;
  const int wm = wid >> 2, wn = wid & 3;
  const int l31 = lane & 31, kh = lane >> 5;

  f32x16 acc[4][2];
  #pragma unroll
  for (int m = 0; m < 4; ++m)
    #pragma unroll
    for (int h = 0; h < 2; ++h)
      acc[m][h] = (f32x16)(0.f);

  // ds_read offsets. A-frag (m, s): row r = wm*128+m*32+l31, k-sub s of 16:
  // region (s>>1)*16K, chunk ((s&1)*2+kh) ^ ((r>>1)&3).
  int aoff[4][4], boff[2][4];
  #pragma unroll
  for (int m = 0; m < 4; ++m) {
    const int r = wm * 128 + m * 32 + l31;
    #pragma unroll
    for (int s = 0; s < 4; ++s)
      aoff[m][s] = (s >> 1) * 16384 + r * 64 +
                   ((((s & 1) * 2 + kh) ^ ((r >> 1) & 3)) * 16);
  }
  #pragma unroll
  for (int jf = 0; jf < 2; ++jf) {
    const int jc = wn * 64 + jf * 32 + l31;
    #pragma unroll
    for (int s = 0; s < 4; ++s)
      boff[jf][s] = 32768 + (s >> 1) * 16384 + jc * 64 +
                    ((((s & 1) * 2 + kh) ^ ((jc >> 1) & 3)) * 16);
  }

  auto SA = [&](int kt, int q, char* buf) {   // stage A half-k q of tile kt
    const int go = kt * 128 + q * 64;
    gload16(sA0 + go, buf + q * 16384 + t * 16);
    gload16(sA1 + go, buf + q * 16384 + 8192 + t * 16);
  };
  auto SB = [&](int kt, int q, char* buf) {   // stage B half-k q of tile kt
    const int go = kt * 128 + q * 64;
    gload16(sB0 + go, buf + 32768 + q * 16384 + t * 16);
    gload16(sB1 + go, buf + 32768 + q * 16384 + 8192 + t * 16);
  };

  bf16x8 af[2][2], bfv[2][2];
  auto LDA2 = [&](const char* cb, int mh, int qq) {
    #pragma unroll
    for (int mm = 0; mm < 2; ++mm)
      #pragma unroll
      for (int ss = 0; ss < 2; ++ss)
        af[mm][ss] = *(const bf16x8*)(cb + aoff[mh * 2 + mm][qq * 2 + ss]);
  };
  auto LDB2 = [&](const char* cb, int qq) {
    #pragma unroll
    for (int jf = 0; jf < 2; ++jf)
      #pragma unroll
      for (int ss = 0; ss < 2; ++ss)
        bfv[jf][ss] = *(const bf16x8*)(cb + boff[jf][qq * 2 + ss]);
  };
  auto MM = [&](int mh) {
    __builtin_amdgcn_s_setprio(1);
    #pragma unroll
    for (int ss = 0; ss < 2; ++ss)
      #pragma unroll
      for (int mm = 0; mm < 2; ++mm)
        #pragma unroll
        for (int jf = 0; jf < 2; ++jf)
          acc[mh * 2 + mm][jf] = __builtin_amdgcn_mfma_f32_32x32x16_bf16(
              af[mm][ss], bfv[jf][ss], acc[mh * 2 + mm][jf], 0, 0, 0);
    __builtin_amdgcn_s_setprio(0);
  };
#define GUARD4 asm volatile("s_waitcnt vmcnt(4)" ::: "memory")
#define GUARD0 asm volatile("s_waitcnt vmcnt(0)" ::: "memory")
#define BAR __builtin_amdgcn_s_barrier()

  // Prologue: stage all 4 halves of tile 0; wait for q0 halves only.
  SA(0, 0, lds); SB(0, 0, lds); SA(0, 1, lds); SB(0, 1, lds);
  GUARD4; BAR;

  for (int k = 0; k < 15; ++k) {
    const char* cb = lds + (k & 1) * 65536;
    char* nb = lds + ((k + 1) & 1) * 65536;
    // P1: q0, m0-1
    LDA2(cb, 0, 0); LDB2(cb, 0);
    SA(k + 1, 0, nb);
    BAR; MM(0); BAR;
    // P2: q0, m2-3 (guard retires this tile's q1 halves for P3)
    LDA2(cb, 1, 0);
    SB(k + 1, 0, nb);
    GUARD4; BAR; MM(1); BAR;
    // P3: q1, m0-1
    LDA2(cb, 0, 1); LDB2(cb, 1);
    SA(k + 1, 1, nb);
    BAR; MM(0); BAR;
    // P4: q1, m2-3 (guard retires next tile's q0 halves for its P1)
    LDA2(cb, 1, 1);
    SB(k + 1, 1, nb);
    GUARD4; BAR; MM(1); BAR;
  }
  {  // Tail tile 15 (buf 1), no staging.
    const char* cb = lds + 65536;
    LDA2(cb, 0, 0); LDB2(cb, 0);
    BAR; MM(0); BAR;
    LDA2(cb, 1, 0);
    GUARD0; BAR; MM(1); BAR;
    LDA2(cb, 0, 1); LDB2(cb, 1);
    BAR; MM(0); BAR;
    LDA2(cb, 1, 1);
    MM(1);
  }
#undef GUARD4
#undef GUARD0
#undef BAR

  // Fused epilogue: acc[m][0]=gate, acc[m][1]=up, same lane -> same out col.
  // C/D 32x32 layout: col = lane&31, row = (reg&3) + 8*(reg>>2) + 4*(lane>>5).
  #pragma unroll
  for (int m = 0; m < 4; ++m) {
    #pragma unroll
    for (int reg = 0; reg < 16; ++reg) {
      const int rl = wm * 128 + m * 32 + (reg & 3) + 8 * (reg >> 2) + 4 * kh;
      if (rl < tile_cnt) {
        float gg = acc[m][0][reg];
        float uu = acc[m][1][reg];
        float s = gg / (1.0f + __expf(-gg)) * uu;
        Out[(size_t)s_rows[rl] * OUTN + c0 + wn * 32 + l31] = s;
      }
    }
  }
}

extern "C" void kernel_launch(void* const* d_in, const int* in_sizes, int n_in,
                              void* d_out, int out_size, void* d_ws, size_t ws_size,
                              hipStream_t stream) {
  const float* H  = (const float*)d_in[0];
  const float* W  = (const float*)d_in[1];
  const int* ids  = (const int*)d_in[2];
  float* Out      = (float*)d_out;
  char* ws        = (char*)d_ws;
  int* wsi        = (int*)ws;
  int* rowlist    = (int*)(ws + WS_ROWLIST);
  unsigned short* Hb = (unsigned short*)(ws + WS_HB);
  unsigned short* Wt = (unsigned short*)(ws + WS_WT);

  hipMemsetAsync(ws, 0, 1024, stream);
  k_detect<<<RFLAT / 2 / 256, 256, 0, stream>>>(ids, wsi);
  k_count<<<RFLAT / 512, 256, 0, stream>>>(ids, wsi);
  k_scan<<<1, 64, 0, stream>>>(wsi);
  k_scatter<<<RFLAT / 256, 256, 0, stream>>>(ids, wsi, rowlist);
  k_cvtH<<<2048, 256, 0, stream>>>(H, Hb);
  k_cvtW<<<dim3(ND / 64, KD / 64, NE), dim3(64, 8), 0, stream>>>(W, Wt);
  // rowtiles (256-row) <= 135; 17 slots per XCD x 8 XCDs x 8 colblocks
  k_gemm<<<8 * 17 * 8, 512, 0, stream>>>(Hb, Wt, wsi, rowlist, Out);
}

// Round 9
// 233.286 us; speedup vs baseline: 1.0728x; 1.0728x over previous
//
#include <hip/hip_runtime.h>
#include <hip/hip_bf16.h>
#include <stdint.h>

typedef __attribute__((ext_vector_type(4))) float f32x4;
typedef __attribute__((ext_vector_type(8))) short bf16x8;
typedef __attribute__((ext_vector_type(4))) float float4v;

static constexpr int KD    = 1024;   // hidden dim
static constexpr int ND    = 2048;   // expert out dim (gate+up)
static constexpr int NE    = 8;      // experts
static constexpr int MROWS = 16384;  // hidden rows
static constexpr int RFLAT = 32768;  // M * topk
static constexpr int OUTN  = 1024;   // output cols (ND/2)

// ws ints: cnt[8]@0, cursor[8]@8, offs[9]@16, mode@31, tileoff[9]@40
static constexpr size_t WS_ROWLIST = 1024;
static constexpr size_t WS_HB      = 262144;
static constexpr size_t WS_WT      = 262144 + (size_t)33554432;

__device__ __forceinline__ unsigned short f2bf(float f) {
  uint32_t u = __float_as_uint(f);
  uint32_t r = (u + 0x7FFFu + ((u >> 16) & 1u)) >> 16;
  return (unsigned short)r;
}

__device__ __forceinline__ void gload16(const void* g, void* l) {
  __builtin_amdgcn_global_load_lds(
      (__attribute__((address_space(1))) void*)(void*)g,
      (__attribute__((address_space(3))) void*)l, 16, 0, 0);
}

// Detect int32-converted vs raw-int64 ids (odd 32-bit slots all zero => int64).
__global__ void k_detect(const int* __restrict__ ids32, int* __restrict__ wsi) {
  int t = blockIdx.x * 256 + threadIdx.x;
  int i = 2 * t + 1;
  if (i < RFLAT && ids32[i] != 0) atomicOr(&wsi[31], 1);
}

__device__ __forceinline__ int read_id(const int* ids32, int t, int mode) {
  return (mode ? ids32[t] : ids32[2 * t]) & 7;
}

// LDS-histogram count.
__global__ void k_count(const int* __restrict__ ids, int* __restrict__ wsi) {
  __shared__ int h[8];
  const int tid = threadIdx.x;
  if (tid < 8) h[tid] = 0;
  __syncthreads();
  const int mode = wsi[31];
  const int base = blockIdx.x * 512 + tid;
  atomicAdd(&h[read_id(ids, base, mode)], 1);
  atomicAdd(&h[read_id(ids, base + 256, mode)], 1);
  __syncthreads();
  if (tid < 8 && h[tid]) atomicAdd(&wsi[tid], h[tid]);
}

__global__ void k_scan(int* wsi) {
  if (threadIdx.x == 0) {
    int o = 0, to = 0;
    for (int e = 0; e < NE; ++e) {
      int c = wsi[e];
      wsi[16 + e] = o;   // offs
      wsi[8 + e]  = o;   // cursor
      wsi[40 + e] = to;  // tile offset (256-row tiles)
      o += c;
      to += (c + 255) / 256;
    }
    wsi[16 + NE] = o;
    wsi[40 + NE] = to;
  }
}

// LDS-histogram scatter: per-block base + local rank.
__global__ void k_scatter(const int* __restrict__ ids, int* __restrict__ wsi,
                          int* __restrict__ rowlist) {
  __shared__ int h[8], base[8], c2[8];
  const int tid = threadIdx.x;
  if (tid < 8) { h[tid] = 0; c2[tid] = 0; }
  __syncthreads();
  const int mode = wsi[31];
  const int t = blockIdx.x * 256 + tid;
  const int e = read_id(ids, t, mode);
  atomicAdd(&h[e], 1);
  __syncthreads();
  if (tid < 8 && h[tid]) base[tid] = atomicAdd(&wsi[8 + tid], h[tid]);
  __syncthreads();
  const int r = atomicAdd(&c2[e], 1);
  rowlist[base[e] + r] = t;
}

__global__ void k_cvtH(const float* __restrict__ H, unsigned short* __restrict__ Hb) {
  const int n4 = (MROWS * KD) / 4;
  const int stride = gridDim.x * blockDim.x;
  for (int i = blockIdx.x * blockDim.x + threadIdx.x; i < n4; i += stride) {
    float4v v = ((const float4v*)H)[i];
    ushort4 o;
    o.x = f2bf(v.x); o.y = f2bf(v.y); o.z = f2bf(v.z); o.w = f2bf(v.w);
    ((ushort4*)Hb)[i] = o;
  }
}

// Transpose + convert: W[e][k][n] fp32 -> Wt[e][n][k] bf16 (64x64 tiles).
__global__ void k_cvtW(const float* __restrict__ W, unsigned short* __restrict__ Wt) {
  __shared__ float tile[64][65];
  const int e  = blockIdx.z;
  const int n0 = blockIdx.x * 64;
  const int k0 = blockIdx.y * 64;
  const int tx = threadIdx.x, ty = threadIdx.y;
  const float* Wp = W + (size_t)e * KD * ND;
  #pragma unroll
  for (int i = ty; i < 64; i += 8)
    tile[i][tx] = Wp[(size_t)(k0 + i) * ND + n0 + tx];
  __syncthreads();
  unsigned short* Wo = Wt + (size_t)e * ND * KD;
  #pragma unroll
  for (int i = ty; i < 64; i += 8)
    Wo[(size_t)(n0 + i) * KD + k0 + tx] = f2bf(tile[tx][i]);
}

// Grouped GEMM: 4-phase schedule, 4-slot LDS ring, 3-half-tile prefetch.
// 256 rows x 256 wcols, BK=64 (2 halves of 32k), 16 K-tiles, 512 threads =
// 8 waves (2Mx4N), wave tile 128x64, acc[8][4], 16x16x32 MFMA.
// LDS: 4 slots x 32KB (A[256]x64B + B[256]x64B); half h -> slot h&3.
// Tile k reads halves 2k (P1,P2) and 2k+1 (P3,P4); P1 stages half 2k+3,
// P3 stages half 2k+4 (slot of half 2k, freed after P2's barrier).
// Guards: vmcnt(8) end-P2 (retires 2k+1, issued 4 phases prior) and end-P4
// (retires 2k+2, issued 6 phases prior). Never vmcnt(0) in main loop.
// Swizzle: slot s of row r holds chunk s ^ ((r>>1)&3); kc=lane>>4 read
// pattern -> 2-way-free b128 (0 conflicts); linear gload dest (rule 21).
__global__ __launch_bounds__(512, 2) void k_gemm(
    const unsigned short* __restrict__ Hb, const unsigned short* __restrict__ Wt,
    const int* __restrict__ wsi, const int* __restrict__ rowlist,
    float* __restrict__ Out) {
  const int bid = blockIdx.x;
  const int xcd = bid & 7;
  const int j   = bid >> 3;
  const int colblk = j & 7;        // col-blocks fastest within an XCD
  const int rt  = xcd + (j >> 3) * 8;
  if (rt >= wsi[48]) return;
  int e = 0;
  #pragma unroll
  for (int q = 1; q < 8; ++q)
    if (rt >= wsi[40 + q]) e = q;
  const int cnt = wsi[e];
  const int tile_base = (rt - wsi[40 + e]) * 256;
  const int tile_cnt = min(256, cnt - tile_base);
  const int off = wsi[16 + e] + tile_base;
  const int c0 = colblk * 128;     // out-col base

  __shared__ char lds[131072];
  __shared__ int s_rows[256];

  const int t = threadIdx.x;
  if (t < 256) s_rows[t] = rowlist[off + min(t, tile_cnt - 1)];
  __syncthreads();

  // Staging: thread t covers rows/cols (t>>2) and 128+(t>>2), slot t&3.
  // Source chunk = (t&3) ^ ((t>>3)&3) pre-applies read swizzle sigma(r)=(r>>1)&3.
  const int srow = t >> 2;
  const int coff = ((t & 3) ^ ((t >> 3) & 3)) * 16;
  const char* sA0 = (const char*)Hb + (size_t)(s_rows[srow] >> 1) * (KD * 2) + coff;
  const char* sA1 = (const char*)Hb + (size_t)(s_rows[128 + srow] >> 1) * (KD * 2) + coff;
  auto wcol_of = [&](int jc) {
    const int wn_s = jc >> 6, r64 = jc & 63;
    const int h_s = r64 >> 4, l_s = r64 & 15;
    return (h_s < 2) ? (c0 + wn_s * 32 + h_s * 16 + l_s)
                     : (OUTN + c0 + wn_s * 32 + (h_s - 2) * 16 + l_s);
  };
  const char* sB0 = (const char*)Wt + ((size_t)e * ND + wcol_of(srow)) * (KD * 2) + coff;
  const char* sB1 = (const char*)Wt + ((size_t)e * ND + wcol_of(128 + srow)) * (KD * 2) + coff;

  const int lane = t & 63, wid = t >> 6;
  const int wm = wid >> 2, wn = wid & 3;
  const int kc = lane >> 4, l15 = lane & 15;

  f32x4 acc[8][4];
  #pragma unroll
  for (int m = 0; m < 8; ++m)
    #pragma unroll
    for (int h = 0; h < 4; ++h)
      acc[m][h] = (f32x4){0.f, 0.f, 0.f, 0.f};

  // Slot-relative ds_read offsets: A row r @ r*64, B col j @ 16K + j*64,
  // chunk = kc ^ ((row>>1)&3).
  int aoff[8], boff[4];
  #pragma unroll
  for (int m = 0; m < 8; ++m) {
    const int r = wm * 128 + m * 16 + l15;
    aoff[m] = r * 64 + ((kc ^ ((r >> 1) & 3)) * 16);
  }
  #pragma unroll
  for (int h = 0; h < 4; ++h) {
    const int jc = wn * 64 + h * 16 + l15;
    boff[h] = 16384 + jc * 64 + ((kc ^ ((jc >> 1) & 3)) * 16);
  }

  auto SAB = [&](int h, char* slot) {   // stage half h (64B/row) into slot
    const int go = h * 64;
    gload16(sA0 + go, slot + t * 16);
    gload16(sA1 + go, slot + 8192 + t * 16);
    gload16(sB0 + go, slot + 16384 + t * 16);
    gload16(sB1 + go, slot + 24576 + t * 16);
  };

  bf16x8 af[4], bfv[4];
  auto LDA = [&](const char* cb, int mlo) {
    #pragma unroll
    for (int m = 0; m < 4; ++m) af[m] = *(const bf16x8*)(cb + aoff[mlo + m]);
  };
  auto LDB = [&](const char* cb) {
    #pragma unroll
    for (int h = 0; h < 4; ++h) bfv[h] = *(const bf16x8*)(cb + boff[h]);
  };
  auto MM = [&](int mlo) {
    __builtin_amdgcn_s_setprio(1);
    #pragma unroll
    for (int m = 0; m < 4; ++m)
      #pragma unroll
      for (int h = 0; h < 4; ++h)
        acc[mlo + m][h] =
            __builtin_amdgcn_mfma_f32_16x16x32_bf16(af[m], bfv[h], acc[mlo + m][h], 0, 0, 0);
    __builtin_amdgcn_s_setprio(0);
  };
#define GUARD8 asm volatile("s_waitcnt vmcnt(8)" ::: "memory")
#define GUARD4 asm volatile("s_waitcnt vmcnt(4)" ::: "memory")
#define GUARD0 asm volatile("s_waitcnt vmcnt(0)" ::: "memory")
#define BAR __builtin_amdgcn_s_barrier()

  // Prologue: stage halves 0,1,2 (12 loads); retire half 0; sync.
  SAB(0, lds);
  SAB(1, lds + 32768);
  SAB(2, lds + 65536);
  GUARD8; BAR;

  for (int k = 0; k < 14; ++k) {
    char* cb0 = lds + (k & 1) * 65536;            // half 2k   (slot 2k&3)
    char* cb1 = cb0 + 32768;                      // half 2k+1
    char* st1 = lds + ((k + 1) & 1) * 65536 + 32768;  // slot for half 2k+3
    // P1
    LDA(cb0, 0); LDB(cb0);
    SAB(2 * k + 3, st1);
    BAR; MM(0); BAR;
    // P2 (guard retires half 2k+1, needed by P3)
    LDA(cb0, 4);
    GUARD8; BAR; MM(4); BAR;
    // P3 (stage half 2k+4 into half-2k's slot, freed by P2's barrier)
    LDA(cb1, 0); LDB(cb1);
    SAB(2 * k + 4, cb0);
    BAR; MM(0); BAR;
    // P4 (guard retires half 2k+2, needed by next tile's P1)
    LDA(cb1, 4);
    GUARD8; BAR; MM(4); BAR;
  }
  {  // Tile 14: stage half 31 only (no half 32).
    char* cb0 = lds;            // half 28 (slot 0)
    char* cb1 = lds + 32768;    // half 29
    char* st1 = lds + 98304;    // slot 3 for half 31
    LDA(cb0, 0); LDB(cb0);
    SAB(31, st1);
    BAR; MM(0); BAR;
    LDA(cb0, 4);
    GUARD8; BAR; MM(4); BAR;    // retires 29; {30,31} in flight
    LDA(cb1, 0); LDB(cb1);
    BAR; MM(0); BAR;
    LDA(cb1, 4);
    GUARD4; BAR; MM(4); BAR;    // retires 30
  }
  {  // Tile 15: halves 30 (slot 2), 31 (slot 3); drain.
    char* cb0 = lds + 65536;
    char* cb1 = lds + 98304;
    LDA(cb0, 0); LDB(cb0);
    BAR; MM(0); BAR;
    LDA(cb0, 4);
    GUARD0; BAR; MM(4); BAR;    // retires 31
    LDA(cb1, 0); LDB(cb1);
    BAR; MM(0); BAR;
    LDA(cb1, 4);
    MM(4);
  }
#undef GUARD8
#undef GUARD4
#undef GUARD0
#undef BAR

  // Fused epilogue: gate = acc[m][h], up = acc[m][h+2], h in {0,1}.
  #pragma unroll
  for (int m = 0; m < 8; ++m) {
    const int rbase = wm * 128 + m * 16 + kc * 4;
    #pragma unroll
    for (int i = 0; i < 4; ++i) {
      const int rl = rbase + i;
      if (rl < tile_cnt) {
        const size_t orow = (size_t)s_rows[rl] * OUTN;
        #pragma unroll
        for (int h = 0; h < 2; ++h) {
          float gg = acc[m][h][i];
          float uu = acc[m][h + 2][i];
          float s = gg / (1.0f + __expf(-gg)) * uu;
          Out[orow + c0 + wn * 32 + h * 16 + l15] = s;
        }
      }
    }
  }
}

extern "C" void kernel_launch(void* const* d_in, const int* in_sizes, int n_in,
                              void* d_out, int out_size, void* d_ws, size_t ws_size,
                              hipStream_t stream) {
  const float* H  = (const float*)d_in[0];
  const float* W  = (const float*)d_in[1];
  const int* ids  = (const int*)d_in[2];
  float* Out      = (float*)d_out;
  char* ws        = (char*)d_ws;
  int* wsi        = (int*)ws;
  int* rowlist    = (int*)(ws + WS_ROWLIST);
  unsigned short* Hb = (unsigned short*)(ws + WS_HB);
  unsigned short* Wt = (unsigned short*)(ws + WS_WT);

  hipMemsetAsync(ws, 0, 1024, stream);
  k_detect<<<RFLAT / 2 / 256, 256, 0, stream>>>(ids, wsi);
  k_count<<<RFLAT / 512, 256, 0, stream>>>(ids, wsi);
  k_scan<<<1, 64, 0, stream>>>(wsi);
  k_scatter<<<RFLAT / 256, 256, 0, stream>>>(ids, wsi, rowlist);
  k_cvtH<<<2048, 256, 0, stream>>>(H, Hb);
  k_cvtW<<<dim3(ND / 64, KD / 64, NE), dim3(64, 8), 0, stream>>>(W, Wt);
  // rowtiles (256-row) <= 135; 17 slots per XCD x 8 XCDs x 8 colblocks
  k_gemm<<<8 * 17 * 8, 512, 0, stream>>>(Hb, Wt, wsi, rowlist, Out);
}

// Round 10
// 228.204 us; speedup vs baseline: 1.0967x; 1.0223x over previous
//
#include <hip/hip_runtime.h>
#include <hip/hip_bf16.h>
#include <stdint.h>

typedef __attribute__((ext_vector_type(4))) float f32x4;
typedef __attribute__((ext_vector_type(8))) short bf16x8;
typedef __attribute__((ext_vector_type(4))) float float4v;

static constexpr int KD    = 1024;   // hidden dim
static constexpr int ND    = 2048;   // expert out dim (gate+up)
static constexpr int NE    = 8;      // experts
static constexpr int MROWS = 16384;  // hidden rows
static constexpr int RFLAT = 32768;  // M * topk
static constexpr int OUTN  = 1024;   // output cols (ND/2)

// ws ints: cnt[8]@0, cursor[8]@8, offs[9]@16, mode@31, tileoff[9]@40
static constexpr size_t WS_ROWLIST = 1024;
static constexpr size_t WS_HB      = 262144;
static constexpr size_t WS_WT      = 262144 + (size_t)33554432;

__device__ __forceinline__ unsigned short f2bf(float f) {
  uint32_t u = __float_as_uint(f);
  uint32_t r = (u + 0x7FFFu + ((u >> 16) & 1u)) >> 16;
  return (unsigned short)r;
}

__device__ __forceinline__ void gload16(const void* g, void* l) {
  __builtin_amdgcn_global_load_lds(
      (__attribute__((address_space(1))) void*)(void*)g,
      (__attribute__((address_space(3))) void*)l, 16, 0, 0);
}

// Detect int32-converted vs raw-int64 ids (odd 32-bit slots all zero => int64).
__global__ void k_detect(const int* __restrict__ ids32, int* __restrict__ wsi) {
  int t = blockIdx.x * 256 + threadIdx.x;
  int i = 2 * t + 1;
  if (i < RFLAT && ids32[i] != 0) atomicOr(&wsi[31], 1);
}

__device__ __forceinline__ int read_id(const int* ids32, int t, int mode) {
  return (mode ? ids32[t] : ids32[2 * t]) & 7;
}

// LDS-histogram count.
__global__ void k_count(const int* __restrict__ ids, int* __restrict__ wsi) {
  __shared__ int h[8];
  const int tid = threadIdx.x;
  if (tid < 8) h[tid] = 0;
  __syncthreads();
  const int mode = wsi[31];
  const int base = blockIdx.x * 512 + tid;
  atomicAdd(&h[read_id(ids, base, mode)], 1);
  atomicAdd(&h[read_id(ids, base + 256, mode)], 1);
  __syncthreads();
  if (tid < 8 && h[tid]) atomicAdd(&wsi[tid], h[tid]);
}

__global__ void k_scan(int* wsi) {
  if (threadIdx.x == 0) {
    int o = 0, to = 0;
    for (int e = 0; e < NE; ++e) {
      int c = wsi[e];
      wsi[16 + e] = o;   // offs
      wsi[8 + e]  = o;   // cursor
      wsi[40 + e] = to;  // tile offset (256-row tiles)
      o += c;
      to += (c + 255) / 256;
    }
    wsi[16 + NE] = o;
    wsi[40 + NE] = to;
  }
}

// LDS-histogram scatter: per-block base + local rank.
__global__ void k_scatter(const int* __restrict__ ids, int* __restrict__ wsi,
                          int* __restrict__ rowlist) {
  __shared__ int h[8], base[8], c2[8];
  const int tid = threadIdx.x;
  if (tid < 8) { h[tid] = 0; c2[tid] = 0; }
  __syncthreads();
  const int mode = wsi[31];
  const int t = blockIdx.x * 256 + tid;
  const int e = read_id(ids, t, mode);
  atomicAdd(&h[e], 1);
  __syncthreads();
  if (tid < 8 && h[tid]) base[tid] = atomicAdd(&wsi[8 + tid], h[tid]);
  __syncthreads();
  const int r = atomicAdd(&c2[e], 1);
  rowlist[base[e] + r] = t;
}

__global__ void k_cvtH(const float* __restrict__ H, unsigned short* __restrict__ Hb) {
  const int n4 = (MROWS * KD) / 4;
  const int stride = gridDim.x * blockDim.x;
  for (int i = blockIdx.x * blockDim.x + threadIdx.x; i < n4; i += stride) {
    float4v v = ((const float4v*)H)[i];
    ushort4 o;
    o.x = f2bf(v.x); o.y = f2bf(v.y); o.z = f2bf(v.z); o.w = f2bf(v.w);
    ((ushort4*)Hb)[i] = o;
  }
}

// Transpose + convert: W[e][k][n] fp32 -> Wt[e][n][k] bf16 (64x64 tiles,
// 16B vectorized stores).
__global__ void k_cvtW(const float* __restrict__ W, unsigned short* __restrict__ Wt) {
  __shared__ float tile[64][65];
  const int e  = blockIdx.z;
  const int n0 = blockIdx.x * 64;
  const int k0 = blockIdx.y * 64;
  const int t  = threadIdx.x;          // 512
  const int tx = t & 63, ty = t >> 6;  // load phase: 64 x 8
  const float* Wp = W + (size_t)e * KD * ND;
  #pragma unroll
  for (int i = ty; i < 64; i += 8)
    tile[i][tx] = Wp[(size_t)(k0 + i) * ND + n0 + tx];
  __syncthreads();
  // store phase: thread -> n = t>>3, k-chunk = (t&7)*8; one 16B store
  const int n = t >> 3, kc8 = (t & 7) * 8;
  ushort4 o0, o1;
  o0.x = f2bf(tile[kc8 + 0][n]); o0.y = f2bf(tile[kc8 + 1][n]);
  o0.z = f2bf(tile[kc8 + 2][n]); o0.w = f2bf(tile[kc8 + 3][n]);
  o1.x = f2bf(tile[kc8 + 4][n]); o1.y = f2bf(tile[kc8 + 5][n]);
  o1.z = f2bf(tile[kc8 + 6][n]); o1.w = f2bf(tile[kc8 + 7][n]);
  unsigned short* Wo = Wt + (size_t)e * ND * KD + (size_t)(n0 + n) * KD + k0 + kc8;
  *(ushort4*)Wo = o0;
  *(ushort4*)(Wo + 4) = o1;
}

// Grouped GEMM: 4-phase counted-vmcnt schedule, 3-slot LDS ring, 2 blocks/CU.
// 256 rows x 128 wcols (64 gate + 64 up), BK=64 (2 halves of 32k), 16 K-tiles,
// 256 threads = 4 waves (2M x 2N), wave tile 128 rows x 64 wcols, acc[8][4],
// 16x16x32 MFMA. LDS: 3 slots x 24KB (A[256]x64B @0, B[128]x64B @16K) +
// s_rows = 74.7KB -> 2 independent blocks/CU whose waves interleave freely
// (cross-block overlap hides barrier/lgkm stalls).
// Half h -> slot h%3. Tile k reads halves 2k (P1,P2), 2k+1 (P3,P4);
// P1 stages half 2k+2, P3 stages half 2k+3 (into slots freed >=2 barriers ago).
// Guards: vmcnt(6) end-P2 / end-P4 retire the half needed one phase later,
// issued 4 phases earlier. Never vmcnt(0) in the main loop.
// Swizzle: slot s of row r holds chunk s ^ ((r>>1)&3) -> conflict-free b128;
// linear gload dest + pre-swizzled source (rule 21).
__global__ __launch_bounds__(256, 2) void k_gemm(
    const unsigned short* __restrict__ Hb, const unsigned short* __restrict__ Wt,
    const int* __restrict__ wsi, const int* __restrict__ rowlist,
    float* __restrict__ Out) {
  const int bid = blockIdx.x;
  const int xcd = bid & 7;
  const int j   = bid >> 3;
  const int colblk = j & 15;       // col-blocks fastest within an XCD
  const int rt  = xcd + (j >> 4) * 8;
  if (rt >= wsi[48]) return;
  int e = 0;
  #pragma unroll
  for (int q = 1; q < 8; ++q)
    if (rt >= wsi[40 + q]) e = q;
  const int cnt = wsi[e];
  const int tile_base = (rt - wsi[40 + e]) * 256;
  const int tile_cnt = min(256, cnt - tile_base);
  const int off = wsi[16 + e] + tile_base;
  const int c0 = colblk * 64;      // out-col base

  constexpr int SLOT = 24576;
  __shared__ char lds[3 * SLOT];
  __shared__ int s_rows[256];

  const int t = threadIdx.x;
  s_rows[t] = rowlist[off + min(t, tile_cnt - 1)];
  __syncthreads();

  // Staging: thread t covers row/col (t>>2)+u*64, slot chunk t&3.
  // Source chunk = (t&3) ^ ((t>>3)&3) pre-applies read swizzle sigma(r)=(r>>1)&3.
  const int coff = ((t & 3) ^ ((t >> 3) & 3)) * 16;
  const char* srcA[4];
  const char* srcB[2];
  #pragma unroll
  for (int u = 0; u < 4; ++u)
    srcA[u] = (const char*)Hb +
              (size_t)(s_rows[u * 64 + (t >> 2)] >> 1) * (KD * 2) + coff;
  auto wcol_of = [&](int jc) {   // jc in [0,128)
    const int wn_s = jc >> 6, r64 = jc & 63;
    const int h_s = r64 >> 4, l_s = r64 & 15;
    return (h_s < 2) ? (c0 + wn_s * 32 + h_s * 16 + l_s)
                     : (OUTN + c0 + wn_s * 32 + (h_s - 2) * 16 + l_s);
  };
  #pragma unroll
  for (int u = 0; u < 2; ++u)
    srcB[u] = (const char*)Wt +
              ((size_t)e * ND + wcol_of(u * 64 + (t >> 2))) * (KD * 2) + coff;

  const int lane = t & 63, wid = t >> 6;
  const int wm = wid >> 1, wn = wid & 1;
  const int kc = lane >> 4, l15 = lane & 15;

  f32x4 acc[8][4];
  #pragma unroll
  for (int m = 0; m < 8; ++m)
    #pragma unroll
    for (int h = 0; h < 4; ++h)
      acc[m][h] = (f32x4){0.f, 0.f, 0.f, 0.f};

  // Slot-relative ds_read offsets: A row r @ r*64, B col j @ 16K + j*64,
  // chunk = kc ^ ((row>>1)&3).
  int aoff[8], boff[4];
  #pragma unroll
  for (int m = 0; m < 8; ++m) {
    const int r = wm * 128 + m * 16 + l15;
    aoff[m] = r * 64 + ((kc ^ ((r >> 1) & 3)) * 16);
  }
  #pragma unroll
  for (int h = 0; h < 4; ++h) {
    const int jc = wn * 64 + h * 16 + l15;
    boff[h] = 16384 + jc * 64 + ((kc ^ ((jc >> 1) & 3)) * 16);
  }

  auto SAB = [&](int h, char* slot) {   // stage half h: 6 loads/thread
    const int go = h * 64;
    gload16(srcA[0] + go, slot + t * 16);
    gload16(srcA[1] + go, slot + 4096 + t * 16);
    gload16(srcA[2] + go, slot + 8192 + t * 16);
    gload16(srcA[3] + go, slot + 12288 + t * 16);
    gload16(srcB[0] + go, slot + 16384 + t * 16);
    gload16(srcB[1] + go, slot + 20480 + t * 16);
  };

  bf16x8 af[4], bfv[4];
  auto LDA = [&](const char* cb, int mlo) {
    #pragma unroll
    for (int m = 0; m < 4; ++m) af[m] = *(const bf16x8*)(cb + aoff[mlo + m]);
  };
  auto LDB = [&](const char* cb) {
    #pragma unroll
    for (int h = 0; h < 4; ++h) bfv[h] = *(const bf16x8*)(cb + boff[h]);
  };
  auto MM = [&](int mlo) {
    __builtin_amdgcn_s_setprio(1);
    #pragma unroll
    for (int m = 0; m < 4; ++m)
      #pragma unroll
      for (int h = 0; h < 4; ++h)
        acc[mlo + m][h] =
            __builtin_amdgcn_mfma_f32_16x16x32_bf16(af[m], bfv[h], acc[mlo + m][h], 0, 0, 0);
    __builtin_amdgcn_s_setprio(0);
  };
#define GUARD6 asm volatile("s_waitcnt vmcnt(6)" ::: "memory")
#define GUARD0 asm volatile("s_waitcnt vmcnt(0)" ::: "memory")
#define BAR __builtin_amdgcn_s_barrier()

  // Prologue: stage halves 0,1 (12 loads); retire half 0; sync.
  SAB(0, lds);
  SAB(1, lds + SLOT);
  GUARD6; BAR;

  for (int k = 0; k < 15; ++k) {
    char* cb0 = lds + ((2 * k) % 3) * SLOT;      // half 2k
    char* cb1 = lds + ((2 * k + 1) % 3) * SLOT;  // half 2k+1
    char* st0 = lds + ((2 * k + 2) % 3) * SLOT;  // slot for half 2k+2
    // P1 (stage half 2k+2; its slot's last reader passed prev-tile P4 barrier)
    LDA(cb0, 0); LDB(cb0);
    SAB(2 * k + 2, st0);
    BAR; MM(0); BAR;
    // P2 (guard retires half 2k+1, needed by P3; issued 4 phases prior)
    LDA(cb0, 4);
    GUARD6; BAR; MM(4); BAR;
    // P3 (stage half 2k+3 into half-2k's slot, freed by P2's barrier)
    LDA(cb1, 0); LDB(cb1);
    SAB(2 * k + 3, cb0);
    BAR; MM(0); BAR;
    // P4 (guard retires half 2k+2, needed by next tile's P1)
    LDA(cb1, 4);
    GUARD6; BAR; MM(4); BAR;
  }
  {  // Tail tile 15: halves 30 (slot 0), 31 (slot 1); no staging.
    char* cb0 = lds;
    char* cb1 = lds + SLOT;
    LDA(cb0, 0); LDB(cb0);
    BAR; MM(0); BAR;
    LDA(cb0, 4);
    GUARD0; BAR; MM(4); BAR;   // retire half 31
    LDA(cb1, 0); LDB(cb1);
    BAR; MM(0); BAR;
    LDA(cb1, 4);
    MM(4);
  }
#undef GUARD6
#undef GUARD0
#undef BAR

  // Fused epilogue: gate = acc[m][h], up = acc[m][h+2], h in {0,1}.
  #pragma unroll
  for (int m = 0; m < 8; ++m) {
    const int rbase = wm * 128 + m * 16 + kc * 4;
    #pragma unroll
    for (int i = 0; i < 4; ++i) {
      const int rl = rbase + i;
      if (rl < tile_cnt) {
        const size_t orow = (size_t)s_rows[rl] * OUTN;
        #pragma unroll
        for (int h = 0; h < 2; ++h) {
          float gg = acc[m][h][i];
          float uu = acc[m][h + 2][i];
          float s = gg / (1.0f + __expf(-gg)) * uu;
          Out[orow + c0 + wn * 32 + h * 16 + l15] = s;
        }
      }
    }
  }
}

extern "C" void kernel_launch(void* const* d_in, const int* in_sizes, int n_in,
                              void* d_out, int out_size, void* d_ws, size_t ws_size,
                              hipStream_t stream) {
  const float* H  = (const float*)d_in[0];
  const float* W  = (const float*)d_in[1];
  const int* ids  = (const int*)d_in[2];
  float* Out      = (float*)d_out;
  char* ws        = (char*)d_ws;
  int* wsi        = (int*)ws;
  int* rowlist    = (int*)(ws + WS_ROWLIST);
  unsigned short* Hb = (unsigned short*)(ws + WS_HB);
  unsigned short* Wt = (unsigned short*)(ws + WS_WT);

  hipMemsetAsync(ws, 0, 1024, stream);
  k_detect<<<RFLAT / 2 / 256, 256, 0, stream>>>(ids, wsi);
  k_count<<<RFLAT / 512, 256, 0, stream>>>(ids, wsi);
  k_scan<<<1, 64, 0, stream>>>(wsi);
  k_scatter<<<RFLAT / 256, 256, 0, stream>>>(ids, wsi, rowlist);
  k_cvtH<<<2048, 256, 0, stream>>>(H, Hb);
  k_cvtW<<<dim3(ND / 64, KD / 64, NE), 512, 0, stream>>>(W, Wt);
  // rowtiles (256-row) <= 136: 17 slots/XCD x 8 XCDs x 16 colblocks
  k_gemm<<<8 * 17 * 16, 256, 0, stream>>>(Hb, Wt, wsi, rowlist, Out);
}